// Round 16
// baseline (403.670 us; speedup 1.0000x reference)
//
#include <hip/hip_runtime.h>
#include <hip/hip_bf16.h>
#include <cstdint>
#include <cstddef>

// ---- types ----
typedef __bf16 bf16x8 __attribute__((ext_vector_type(8)));   // 16B
typedef __bf16 bf16x4 __attribute__((ext_vector_type(4)));   // 8B
typedef float  f32x4  __attribute__((ext_vector_type(4)));
typedef float  f32x16 __attribute__((ext_vector_type(16)));

#define SCALE_QK 0.17677669529663687f   // 1/sqrt(32)
#define V_SIZE 50257
#define T_SEQ  2048
#define E_DIM  256
#define NROWS  4096                      // B*T
#define LNB    197                       // ceil(50257/256) logits col-blocks (BN=256)
#define NPAD   (LNB * 256)               // 50432, padded vocab rows

__device__ __forceinline__ f32x4 mfma16(bf16x8 a, bf16x8 b, f32x4 c) {
    return __builtin_amdgcn_mfma_f32_16x16x32_bf16(a, b, c, 0, 0, 0);
}
__device__ __forceinline__ f32x16 mfma32(bf16x8 a, bf16x8 b, f32x16 c) {
    return __builtin_amdgcn_mfma_f32_32x32x16_bf16(a, b, c, 0, 0, 0);
}

// async global->LDS, 16B per lane; LDS dest must be wave-uniform base (lane*16 added by HW)
#define GLOAD_LDS16(gptr, lptr) \
    __builtin_amdgcn_global_load_lds((const __attribute__((address_space(1))) void*)(gptr), \
                                     (__attribute__((address_space(3))) void*)(lptr), 16, 0, 0)

// ---- fused prep: embed + Wqkv pack + Wlm cvt/pad + Dcol zero (one launch) ----
#define PREP_EMBED 1024                  // 4 rows each
#define PREP_WQKV  (PREP_EMBED + 768)
#define PREP_CVT   (PREP_WQKV + 12608)   // NPAD*E_DIM/1024
#define PREP_ZERO  (PREP_CVT + 128)      // 16*T_SEQ/256
__global__ void __launch_bounds__(256)
k_prep(const int* __restrict__ idx, const float* __restrict__ tok,
       const float* __restrict__ pos, __bf16* __restrict__ X,
       const float* __restrict__ Wq, const float* __restrict__ Wk,
       const float* __restrict__ Wv, __bf16* __restrict__ Wo,
       const float* __restrict__ Wlm, __bf16* __restrict__ WlmB,
       float* __restrict__ Dcol) {
    const int bx = blockIdx.x, tid = threadIdx.x;
    if (bx < PREP_EMBED) {
        int row = bx * 4 + (tid >> 6);
        int tl = row & (T_SEQ - 1);
        int tk = idx[row];
        int e = (tid & 63) * 4;
        f32x4 a = *(const f32x4*)(tok + (size_t)tk * E_DIM + e);
        f32x4 p = *(const f32x4*)(pos + (size_t)tl * E_DIM + e);
        bf16x4 o;
#pragma unroll
        for (int i = 0; i < 4; ++i) o[i] = (__bf16)(a[i] + p[i]);
        *(bf16x4*)(X + (size_t)row * E_DIM + e) = o;
    } else if (bx < PREP_WQKV) {
        int n = bx - PREP_EMBED;         // 0..767
        int sel = n >> 8, hd = n & 255, h = hd >> 5, d = hd & 31;
        const float* W = (sel == 0) ? Wq : (sel == 1) ? Wk : Wv;
        Wo[(size_t)n * E_DIM + tid] = (__bf16)W[((size_t)h * E_DIM + tid) * 32 + d];
    } else if (bx < PREP_CVT) {
        size_t i = ((size_t)(bx - PREP_WQKV) * 256 + tid) * 4;
        bf16x4 o = {};
        if (i + 4 <= (size_t)V_SIZE * E_DIM) {
            f32x4 v = *(const f32x4*)(Wlm + i);
#pragma unroll
            for (int j = 0; j < 4; ++j) o[j] = (__bf16)v[j];
        }
        *(bf16x4*)(WlmB + i) = o;
    } else {
        Dcol[(bx - PREP_CVT) * 256 + tid] = 0.f;
    }
}

// ---- QKV GEMM: C[M,N] = A[M,K]*B[N,K]^T, bf16 out. BM=BN=128, BK=64, single-buffered ----
template <int KK>
__global__ void __launch_bounds__(256, 4)
k_gemm_bt(const __bf16* __restrict__ A, const __bf16* __restrict__ B,
          __bf16* __restrict__ Cout, int N) {
    __shared__ __align__(16) __bf16 Alds[128 * 64];
    __shared__ __align__(16) __bf16 Blds[128 * 64];

    const int tid = threadIdx.x;
    const int lane = tid & 63, w = tid >> 6;
    const int wr = w >> 1, wc = w & 1;
    const int brow = blockIdx.x * 128, bcol = blockIdx.y * 128;
    const int gg = lane >> 4, li = lane & 15;

    f32x4 acc[4][4] = {};

#pragma unroll
    for (int t = 0; t < KK / 64; ++t) {
#pragma unroll
        for (int i = 0; i < 4; ++i) {
            int cb = (w * 4 + i) * 64;
            int c = cb + lane;
            int r = c >> 3, kbs = (c & 7) ^ (r & 7);
            GLOAD_LDS16(A + (size_t)(brow + r) * KK + t * 64 + kbs * 8, (char*)Alds + cb * 16);
            GLOAD_LDS16(B + (size_t)(bcol + r) * KK + t * 64 + kbs * 8, (char*)Blds + cb * 16);
        }
        __syncthreads();
#pragma unroll
        for (int ks = 0; ks < 2; ++ks) {
            bf16x8 af[4], bfr[4];
#pragma unroll
            for (int mi = 0; mi < 4; ++mi) {
                int r = wr * 64 + mi * 16 + li;
                int kbyte = (ks * 64 + gg * 16) ^ ((r & 7) << 4);
                af[mi] = *(const bf16x8*)((const char*)Alds + r * 128 + kbyte);
            }
#pragma unroll
            for (int ni = 0; ni < 4; ++ni) {
                int r = wc * 64 + ni * 16 + li;
                int kbyte = (ks * 64 + gg * 16) ^ ((r & 7) << 4);
                bfr[ni] = *(const bf16x8*)((const char*)Blds + r * 128 + kbyte);
            }
#pragma unroll
            for (int mi = 0; mi < 4; ++mi)
#pragma unroll
                for (int ni = 0; ni < 4; ++ni)
                    acc[mi][ni] = mfma16(bfr[ni], af[mi], acc[mi][ni]);
        }
        if (t + 1 < KK / 64) __syncthreads();
    }
    // m = brow + wr*64 + mi*16 + li (lane), n = bcol + wc*64 + ni*16 + gg*4 + j (reg)
#pragma unroll
    for (int mi = 0; mi < 4; ++mi) {
        const size_t mrow = (size_t)(brow + wr * 64 + mi * 16 + li) * N;
#pragma unroll
        for (int ni = 0; ni < 4; ++ni) {
            int nc = wc * 64 + ni * 16 + gg * 4;
            f32x4 v = acc[mi][ni];
            bf16x4 o;
#pragma unroll
            for (int j = 0; j < 4; ++j) o[j] = (__bf16)v[j];
            *(bf16x4*)(Cout + mrow + bcol + nc) = o;
        }
    }
}

// ---- logits GEMM: BM=128, BN=256, BK=64, 512 threads (8 waves 2x4) ----
// r14 champion + COLSWAP grid (bn = blockIdx.x, fastest): concurrent block set covers
// ~197 col-tiles x ~2.6 row-panels => active write window ~333 rows (67MB) instead of
// all 4096 rows (823MB) -> fewer HBM page conflicts at 1KB-segment granularity.
__global__ void __launch_bounds__(512, 4)
k_logits(const __bf16* __restrict__ A, const __bf16* __restrict__ B,
         float* __restrict__ C, const float* __restrict__ bias,
         float* __restrict__ partials) {
    __shared__ __align__(16) char smem[49152];   // K-loop: A@0 16KB, B@16384 32KB; epi: 32KB
    __shared__ __align__(16) float bias_lds[256];
    __shared__ float wsum[128][4];

    const int tid = threadIdx.x, lane = tid & 63, w = tid >> 6;   // w 0..7
    const int wr = w >> 2, wc = w & 3;                            // 2 x 4 wave grid
    const int brow = blockIdx.y * 128;                            // COLSWAP: bm = y
    const int bn = blockIdx.x, bcol = bn * 256;                   //          bn = x (fastest)
    const int gg = lane >> 4, li = lane & 15;

    if (tid < 256) bias_lds[tid] = (bcol + tid < V_SIZE) ? bias[bcol + tid] : 0.f;

    f32x4 acc[4][4] = {};

#pragma unroll
    for (int t = 0; t < 4; ++t) {
        // A: 1024 chunks, 2/thread
#pragma unroll
        for (int i = 0; i < 2; ++i) {
            int cb = (w * 2 + i) * 64;
            int c = cb + lane;
            int r = c >> 3, kbs = (c & 7) ^ (r & 7);
            GLOAD_LDS16(A + (size_t)(brow + r) * E_DIM + t * 64 + kbs * 8, smem + cb * 16);
        }
        // B: 2048 chunks, 4/thread
#pragma unroll
        for (int i = 0; i < 4; ++i) {
            int cb = (w * 4 + i) * 64;
            int c = cb + lane;
            int r = c >> 3, kbs = (c & 7) ^ (r & 7);
            GLOAD_LDS16(B + (size_t)(bcol + r) * E_DIM + t * 64 + kbs * 8,
                        smem + 16384 + cb * 16);
        }
        __syncthreads();
#pragma unroll
        for (int ks = 0; ks < 2; ++ks) {
            bf16x8 af[4], bfr[4];
#pragma unroll
            for (int mi = 0; mi < 4; ++mi) {
                int r = wr * 64 + mi * 16 + li;
                int kbyte = (ks * 64 + gg * 16) ^ ((r & 7) << 4);
                af[mi] = *(const bf16x8*)(smem + r * 128 + kbyte);
            }
#pragma unroll
            for (int ni = 0; ni < 4; ++ni) {
                int r = wc * 64 + ni * 16 + li;
                int kbyte = (ks * 64 + gg * 16) ^ ((r & 7) << 4);
                bfr[ni] = *(const bf16x8*)(smem + 16384 + r * 128 + kbyte);
            }
            // swapped operands: register dim <-> B rows (n), lane dim <-> A rows (m)
#pragma unroll
            for (int mi = 0; mi < 4; ++mi)
#pragma unroll
                for (int ni = 0; ni < 4; ++ni)
                    acc[mi][ni] = mfma16(bfr[ni], af[mi], acc[mi][ni]);
        }
        if (t < 3) __syncthreads();
    }

    // epilogue: m = brow + wr*64 + mi*16 + li, n = bcol + wc*64 + ni*16 + gg*4 + j
    if (bcol + 256 <= V_SIZE) {
        // 4 phases x 32 rows: stash (XOR-swizzled) then 1KB-contiguous wave stores
#pragma unroll
        for (int p = 0; p < 4; ++p) {
            __syncthreads();                 // LDS free (K-loop done / prev phase stored)
            if (wr == (p >> 1)) {
#pragma unroll
                for (int m2 = 0; m2 < 2; ++m2) {
                    int mi = (p & 1) * 2 + m2;
                    int rl = m2 * 16 + li;   // local row 0..31 (global = brow + p*32 + rl)
                    float s = 0.f;
#pragma unroll
                    for (int ni = 0; ni < 4; ++ni) {
                        int colc = wc * 16 + ni * 4 + gg;   // 16B col-chunk 0..63
                        f32x4 v = acc[mi][ni];
                        f32x4 bv = *(const f32x4*)&bias_lds[colc * 4];
#pragma unroll
                        for (int j = 0; j < 4; ++j) { v[j] += bv[j]; s += __expf(v[j]); }
                        int c4s = colc ^ ((rl & 7) << 2);
                        *(f32x4*)(smem + rl * 1024 + c4s * 16) = v;
                    }
                    s += __shfl_xor(s, 16); s += __shfl_xor(s, 32);
                    if (gg == 0) wsum[p * 32 + rl][wc] = s;
                }
            }
            __syncthreads();
            // all 8 waves stream 32KB: per instr a wave writes 1KB = one full row segment
#pragma unroll
            for (int i = 0; i < 4; ++i) {
                int c = i * 512 + tid;       // 0..2047
                int rl = c >> 6, c4 = c & 63;
                f32x4 v = *(const f32x4*)(smem + rl * 1024 + ((c4 ^ ((rl & 7) << 2)) << 4));
                *(f32x4*)(C + (size_t)(brow + p * 32 + rl) * V_SIZE + bcol + c4 * 4) = v;
            }
        }
    } else {
        // bn == 196: cols 50176..50256 valid (81) — masked register path
#pragma unroll
        for (int mi = 0; mi < 4; ++mi) {
            const size_t mrow = (size_t)(brow + wr * 64 + mi * 16 + li) * V_SIZE;
            float s = 0.f;
#pragma unroll
            for (int ni = 0; ni < 4; ++ni) {
                int nc = wc * 64 + ni * 16 + gg * 4;
#pragma unroll
                for (int j = 0; j < 4; ++j) {
                    int col = bcol + nc + j;
                    if (col < V_SIZE) {
                        float v = acc[mi][ni][j] + bias_lds[nc + j];
                        s += __expf(v);
                        C[mrow + col] = v;
                    }
                }
            }
            s += __shfl_xor(s, 16); s += __shfl_xor(s, 32);
            if (gg == 0) wsum[wr * 64 + mi * 16 + li][wc] = s;
        }
    }
    __syncthreads();
    if (tid < 128)
        partials[(size_t)bn * NROWS + brow + tid] =
            wsum[tid][0] + wsum[tid][1] + wsum[tid][2] + wsum[tid][3];
}

// ---- attention pass 1: column softmax denominators D[bh][k] = sum_{q>=k} exp(scale*q.k) ----
__global__ void __launch_bounds__(256)
k_pass1(const __bf16* __restrict__ QKV, float* __restrict__ Dcol) {
    int p = blockIdx.x;              // 0..135
    int kt = 0;
    while (p >= 16 - kt) { p -= 16 - kt; ++kt; }
    const int qc = kt + p;
    const int bh = blockIdx.y;
    const int b = bh >> 3, h = bh & 7;
    const int tid = threadIdx.x, lane = tid & 63, w = tid >> 6;
    const int g = lane >> 5, li = lane & 31;
    __shared__ __align__(16) __bf16 Klds[4 * 128 * 8];   // [db][k][8]
    __shared__ __align__(16) __bf16 Qlds[4 * 128 * 8];   // [db][q][8]

    const size_t baseQ = ((size_t)b * T_SEQ) * 768 + h * 32;
    const size_t baseK = baseQ + 256;

#pragma unroll
    for (int i = 0; i < 2; ++i) {
        int c = i * 256 + tid; int k = c >> 2, db = c & 3;
        *(bf16x8*)(Klds + (db * 128 + k) * 8) =
            *(const bf16x8*)(QKV + baseK + (size_t)(kt * 128 + k) * 768 + db * 8);
        *(bf16x8*)(Qlds + (db * 128 + k) * 8) =
            *(const bf16x8*)(QKV + baseQ + (size_t)(qc * 128 + k) * 768 + db * 8);
    }
    __syncthreads();

    float csum = 0.f;
    const int kglob = kt * 128 + w * 32 + li;
#pragma unroll
    for (int qs = 0; qs < 4; ++qs) {
        f32x16 sacc = {};
#pragma unroll
        for (int ks = 0; ks < 2; ++ks) {
            bf16x8 aq = *(const bf16x8*)(Qlds + ((ks * 2 + g) * 128 + qs * 32 + li) * 8);
            bf16x8 bk = *(const bf16x8*)(Klds + ((ks * 2 + g) * 128 + w * 32 + li) * 8);
            sacc = mfma32(aq, bk, sacc);   // S[q][k]: col=l&31=k, row=crow(r,g)=q
        }
#pragma unroll
        for (int r = 0; r < 16; ++r) {
            int qrow = qc * 128 + qs * 32 + ((r & 3) + 8 * (r >> 2) + 4 * g);
            if (kglob <= qrow) csum += __expf(sacc[r] * SCALE_QK);
        }
    }
    csum += __shfl_xor(csum, 32);
    if (g == 0) atomicAdd(&Dcol[(size_t)bh * T_SEQ + kglob], csum);
}

// ---- attention pass 2: y[q][h*32+d] = sum_{k<=q} exp(scale*q.k) * v[k][d] / D[k] ----
__global__ void __launch_bounds__(256)
k_pass2(const __bf16* __restrict__ QKV, const float* __restrict__ Dcol,
        float* __restrict__ Yf0, float* __restrict__ Yf1) {
    const int p = blockIdx.x, bh = blockIdx.y;
    const int pi = p >> 1, par = p & 1;
    const int b = bh >> 3, h = bh & 7;
    const int tid = threadIdx.x, lane = tid & 63, w = tid >> 6;
    const int g = lane >> 5, li = lane & 31;
    float* __restrict__ Yf = par ? Yf1 : Yf0;
    __shared__ __align__(16) __bf16 Qlds[4 * 128 * 8];    // [db][q][8]
    __shared__ __align__(16) __bf16 Klds[4 * 128 * 8];    // [db][k][8]
    __shared__ __align__(16) __bf16 UT[16 * 32 * 8];      // [kb][d][8]  (V/D)^T
    __shared__ __align__(16) __bf16 Plds[4][32 * 136];    // per-wave P[q][k], pad 8

    const size_t baseQ = ((size_t)b * T_SEQ) * 768 + h * 32;
    const size_t baseK = baseQ + 256;
    const size_t baseV = baseQ + 512;

#pragma unroll
    for (int ti = 0; ti < 2; ++ti) {
        const int qt = ti ? (15 - pi) : pi;
        __syncthreads();
#pragma unroll
        for (int i = 0; i < 2; ++i) {
            int c = i * 256 + tid; int q = c >> 2, db = c & 3;
            *(bf16x8*)(Qlds + (db * 128 + q) * 8) =
                *(const bf16x8*)(QKV + baseQ + (size_t)(qt * 128 + q) * 768 + db * 8);
        }
        f32x16 oacc = {};
        const int qrow = qt * 128 + w * 32 + li;

        for (int kc = par; kc <= qt; kc += 2) {
            __syncthreads();
#pragma unroll
            for (int i = 0; i < 2; ++i) {
                int c = i * 256 + tid; int k = c >> 2, db = c & 3;
                *(bf16x8*)(Klds + (db * 128 + k) * 8) =
                    *(const bf16x8*)(QKV + baseK + (size_t)(kc * 128 + k) * 768 + db * 8);
            }
#pragma unroll
            for (int i = 0; i < 4; ++i) {
                int c = i * 256 + tid; int k = c & 127, d4 = c >> 7;
                float rD = 1.0f / Dcol[(size_t)bh * T_SEQ + kc * 128 + k];
                bf16x4 v4 = *(const bf16x4*)(QKV + baseV + (size_t)(kc * 128 + k) * 768 + d4 * 4);
                int kb = k >> 3, j = k & 7;
#pragma unroll
                for (int t2 = 0; t2 < 4; ++t2)
                    UT[((size_t)kb * 32 + d4 * 4 + t2) * 8 + j] = (__bf16)((float)v4[t2] * rD);
            }
            __syncthreads();

#pragma unroll
            for (int ksub = 0; ksub < 4; ++ksub) {
                int kbase = kc * 128 + ksub * 32;
                f32x16 sacc = {};
#pragma unroll
                for (int ks = 0; ks < 2; ++ks) {
                    bf16x8 ak = *(const bf16x8*)(Klds + ((ks * 2 + g) * 128 + ksub * 32 + li) * 8);
                    bf16x8 bq = *(const bf16x8*)(Qlds + ((ks * 2 + g) * 128 + w * 32 + li) * 8);
                    sacc = mfma32(ak, bq, sacc);   // S^T: col=l&31=q, row=crow(r,g)=k
                }
                float pv[16];
#pragma unroll
                for (int r = 0; r < 16; ++r) {
                    int kk = kbase + (r & 3) + 8 * (r >> 2) + 4 * g;
                    pv[r] = (kk <= qrow) ? __expf(sacc[r] * SCALE_QK) : 0.f;
                }
#pragma unroll
                for (int t2 = 0; t2 < 4; ++t2) {
                    bf16x4 pk;
#pragma unroll
                    for (int e = 0; e < 4; ++e) pk[e] = (__bf16)pv[4 * t2 + e];
                    *(bf16x4*)(&Plds[w][li * 136 + ksub * 32 + 8 * t2 + 4 * g]) = pk;
                }
            }
#pragma unroll
            for (int ks16 = 0; ks16 < 8; ++ks16) {
                bf16x8 ap = *(const bf16x8*)(&Plds[w][li * 136 + ks16 * 16 + g * 8]);
                bf16x8 bu = *(const bf16x8*)(UT + ((ks16 * 2 + g) * 32 + li) * 8);
                oacc = mfma32(ap, bu, oacc);       // col=l&31=d, row=crow(r,g)=q
            }
        }
#pragma unroll
        for (int r = 0; r < 16; ++r) {
            int q = qt * 128 + w * 32 + (r & 3) + 8 * (r >> 2) + 4 * g;
            Yf[((size_t)b * T_SEQ + q) * E_DIM + h * 32 + li] = oacc[r];
        }
    }
}

// ---- Y = bf16(Yf0 + Yf1) ----
__global__ void k_ycvt(const float* __restrict__ a, const float* __restrict__ b,
                       __bf16* __restrict__ y, int n4) {
    int i = blockIdx.x * 256 + threadIdx.x;
    if (i < n4) {
        f32x4 va = ((const f32x4*)a)[i], vb = ((const f32x4*)b)[i];
        bf16x4 o;
#pragma unroll
        for (int j = 0; j < 4; ++j) o[j] = (__bf16)(va[j] + vb[j]);
        ((bf16x4*)y)[i] = o;
    }
}

// ---- per-row LSE + target gather ----
__global__ void k_rowlse(const float* __restrict__ partials, const float* __restrict__ logits,
                         const int* __restrict__ tgt, float* __restrict__ rowloss) {
    int r = blockIdx.x * 256 + threadIdx.x;   // 0..4095
    float s = 0.f;
    for (int i = 0; i < LNB; ++i) s += partials[(size_t)i * NROWS + r];
    float lse = logf(s);
    rowloss[r] = lse - logits[(size_t)r * V_SIZE + tgt[r]];
}

// ---- final mean ----
__global__ void k_loss(const float* __restrict__ rowloss, float* __restrict__ out) {
    __shared__ float red[4];
    float s = 0.f;
    for (int i = threadIdx.x; i < NROWS; i += 256) s += rowloss[i];
    for (int m = 1; m < 64; m <<= 1) s += __shfl_xor(s, m);
    if ((threadIdx.x & 63) == 0) red[threadIdx.x >> 6] = s;
    __syncthreads();
    if (threadIdx.x == 0) out[0] = (red[0] + red[1] + red[2] + red[3]) / (float)NROWS;
}

extern "C" void kernel_launch(void* const* d_in, const int* in_sizes, int n_in,
                              void* d_out, int out_size, void* d_ws, size_t ws_size,
                              hipStream_t stream) {
    const int*   idx = (const int*)d_in[0];
    const int*   tgt = (const int*)d_in[1];
    const float* tok = (const float*)d_in[2];
    const float* pos = (const float*)d_in[3];
    const float* Wq  = (const float*)d_in[4];
    const float* Wk  = (const float*)d_in[5];
    const float* Wv  = (const float*)d_in[6];
    const float* Wlm = (const float*)d_in[7];
    const float* blm = (const float*)d_in[8];

    float* logits = (float*)d_out;
    float* loss   = logits + (size_t)NROWS * V_SIZE;

    char* ws = (char*)d_ws;
    __bf16* X        = (__bf16*)ws; ws += (size_t)NROWS * E_DIM * 2;
    __bf16* Wqkv     = (__bf16*)ws; ws += (size_t)768 * E_DIM * 2;
    __bf16* QKV      = (__bf16*)ws; ws += (size_t)NROWS * 768 * 2;
    float*  Dcol     = (float*)ws;  ws += (size_t)16 * T_SEQ * 4;
    __bf16* Y        = (__bf16*)ws; ws += (size_t)NROWS * E_DIM * 2;
    float*  Yf0      = (float*)ws;  ws += (size_t)NROWS * E_DIM * 4;
    float*  Yf1      = (float*)ws;  ws += (size_t)NROWS * E_DIM * 4;
    __bf16* WlmB     = (__bf16*)ws; ws += (size_t)NPAD * E_DIM * 2;   // padded to 50432 rows
    float*  partials = (float*)ws;  ws += (size_t)LNB * NROWS * 4;
    float*  rowloss  = (float*)ws;  ws += (size_t)NROWS * 4;

    k_prep<<<PREP_ZERO, 256, 0, stream>>>(idx, tok, pos, X, Wq, Wk, Wv, Wqkv,
                                          Wlm, WlmB, Dcol);
    k_gemm_bt<E_DIM><<<dim3(NROWS / 128, 768 / 128), 256, 0, stream>>>(
        X, Wqkv, QKV, 768);
    k_pass1<<<dim3(136, 16), 256, 0, stream>>>(QKV, Dcol);
    k_pass2<<<dim3(16, 16), 256, 0, stream>>>(QKV, Dcol, Yf0, Yf1);
    k_ycvt<<<(NROWS * E_DIM / 4 + 255) / 256, 256, 0, stream>>>(Yf0, Yf1, Y, NROWS * E_DIM / 4);
    // COLSWAP grid: bn fastest -> concentrated write window (~333 rows vs 4096)
    k_logits<<<dim3(LNB, NROWS / 128), 512, 0, stream>>>(
        Y, WlmB, logits, blm, partials);
    k_rowlse<<<NROWS / 256, 256, 0, stream>>>(partials, logits, tgt, rowloss);
    k_loss<<<1, 256, 0, stream>>>(rowloss, loss);
}

// Round 17
// 388.417 us; speedup vs baseline: 1.0393x; 1.0393x over previous
//
#include <hip/hip_runtime.h>
#include <hip/hip_bf16.h>
#include <cstdint>
#include <cstddef>

// ---- types ----
typedef __bf16 bf16x8 __attribute__((ext_vector_type(8)));   // 16B
typedef __bf16 bf16x4 __attribute__((ext_vector_type(4)));   // 8B
typedef float  f32x4  __attribute__((ext_vector_type(4)));
typedef float  f32x16 __attribute__((ext_vector_type(16)));

#define SCALE_QK 0.17677669529663687f   // 1/sqrt(32)
#define V_SIZE 50257
#define T_SEQ  2048
#define E_DIM  256
#define NROWS  4096                      // B*T
#define LNB    197                       // ceil(50257/256) logits col-blocks (BN=256)
#define NPAD   (LNB * 256)               // 50432, padded vocab rows

__device__ __forceinline__ f32x4 mfma16(bf16x8 a, bf16x8 b, f32x4 c) {
    return __builtin_amdgcn_mfma_f32_16x16x32_bf16(a, b, c, 0, 0, 0);
}
__device__ __forceinline__ f32x16 mfma32(bf16x8 a, bf16x8 b, f32x16 c) {
    return __builtin_amdgcn_mfma_f32_32x32x16_bf16(a, b, c, 0, 0, 0);
}

// async global->LDS, 16B per lane; LDS dest must be wave-uniform base (lane*16 added by HW)
#define GLOAD_LDS16(gptr, lptr) \
    __builtin_amdgcn_global_load_lds((const __attribute__((address_space(1))) void*)(gptr), \
                                     (__attribute__((address_space(3))) void*)(lptr), 16, 0, 0)

// ---- fused prep: embed + Wqkv pack + Wlm cvt/pad + Dcol zero (one launch) ----
#define PREP_EMBED 1024                  // 4 rows each
#define PREP_WQKV  (PREP_EMBED + 768)
#define PREP_CVT   (PREP_WQKV + 12608)   // NPAD*E_DIM/1024
#define PREP_ZERO  (PREP_CVT + 128)      // 16*T_SEQ/256
__global__ void __launch_bounds__(256)
k_prep(const int* __restrict__ idx, const float* __restrict__ tok,
       const float* __restrict__ pos, __bf16* __restrict__ X,
       const float* __restrict__ Wq, const float* __restrict__ Wk,
       const float* __restrict__ Wv, __bf16* __restrict__ Wo,
       const float* __restrict__ Wlm, __bf16* __restrict__ WlmB,
       float* __restrict__ Dcol) {
    const int bx = blockIdx.x, tid = threadIdx.x;
    if (bx < PREP_EMBED) {
        int row = bx * 4 + (tid >> 6);
        int tl = row & (T_SEQ - 1);
        int tk = idx[row];
        int e = (tid & 63) * 4;
        f32x4 a = *(const f32x4*)(tok + (size_t)tk * E_DIM + e);
        f32x4 p = *(const f32x4*)(pos + (size_t)tl * E_DIM + e);
        bf16x4 o;
#pragma unroll
        for (int i = 0; i < 4; ++i) o[i] = (__bf16)(a[i] + p[i]);
        *(bf16x4*)(X + (size_t)row * E_DIM + e) = o;
    } else if (bx < PREP_WQKV) {
        int n = bx - PREP_EMBED;         // 0..767
        int sel = n >> 8, hd = n & 255, h = hd >> 5, d = hd & 31;
        const float* W = (sel == 0) ? Wq : (sel == 1) ? Wk : Wv;
        Wo[(size_t)n * E_DIM + tid] = (__bf16)W[((size_t)h * E_DIM + tid) * 32 + d];
    } else if (bx < PREP_CVT) {
        size_t i = ((size_t)(bx - PREP_WQKV) * 256 + tid) * 4;
        bf16x4 o = {};
        if (i + 4 <= (size_t)V_SIZE * E_DIM) {
            f32x4 v = *(const f32x4*)(Wlm + i);
#pragma unroll
            for (int j = 0; j < 4; ++j) o[j] = (__bf16)v[j];
        }
        *(bf16x4*)(WlmB + i) = o;
    } else {
        Dcol[(bx - PREP_CVT) * 256 + tid] = 0.f;
    }
}

// ---- QKV GEMM: C[M,N] = A[M,K]*B[N,K]^T, bf16 out. BM=BN=128, BK=64, single-buffered ----
template <int KK>
__global__ void __launch_bounds__(256, 4)
k_gemm_bt(const __bf16* __restrict__ A, const __bf16* __restrict__ B,
          __bf16* __restrict__ Cout, int N) {
    __shared__ __align__(16) __bf16 Alds[128 * 64];
    __shared__ __align__(16) __bf16 Blds[128 * 64];

    const int tid = threadIdx.x;
    const int lane = tid & 63, w = tid >> 6;
    const int wr = w >> 1, wc = w & 1;
    const int brow = blockIdx.x * 128, bcol = blockIdx.y * 128;
    const int gg = lane >> 4, li = lane & 15;

    f32x4 acc[4][4] = {};

#pragma unroll
    for (int t = 0; t < KK / 64; ++t) {
#pragma unroll
        for (int i = 0; i < 4; ++i) {
            int cb = (w * 4 + i) * 64;
            int c = cb + lane;
            int r = c >> 3, kbs = (c & 7) ^ (r & 7);
            GLOAD_LDS16(A + (size_t)(brow + r) * KK + t * 64 + kbs * 8, (char*)Alds + cb * 16);
            GLOAD_LDS16(B + (size_t)(bcol + r) * KK + t * 64 + kbs * 8, (char*)Blds + cb * 16);
        }
        __syncthreads();
#pragma unroll
        for (int ks = 0; ks < 2; ++ks) {
            bf16x8 af[4], bfr[4];
#pragma unroll
            for (int mi = 0; mi < 4; ++mi) {
                int r = wr * 64 + mi * 16 + li;
                int kbyte = (ks * 64 + gg * 16) ^ ((r & 7) << 4);
                af[mi] = *(const bf16x8*)((const char*)Alds + r * 128 + kbyte);
            }
#pragma unroll
            for (int ni = 0; ni < 4; ++ni) {
                int r = wc * 64 + ni * 16 + li;
                int kbyte = (ks * 64 + gg * 16) ^ ((r & 7) << 4);
                bfr[ni] = *(const bf16x8*)((const char*)Blds + r * 128 + kbyte);
            }
#pragma unroll
            for (int mi = 0; mi < 4; ++mi)
#pragma unroll
                for (int ni = 0; ni < 4; ++ni)
                    acc[mi][ni] = mfma16(bfr[ni], af[mi], acc[mi][ni]);
        }
        if (t + 1 < KK / 64) __syncthreads();
    }
    // m = brow + wr*64 + mi*16 + li (lane), n = bcol + wc*64 + ni*16 + gg*4 + j (reg)
#pragma unroll
    for (int mi = 0; mi < 4; ++mi) {
        const size_t mrow = (size_t)(brow + wr * 64 + mi * 16 + li) * N;
#pragma unroll
        for (int ni = 0; ni < 4; ++ni) {
            int nc = wc * 64 + ni * 16 + gg * 4;
            f32x4 v = acc[mi][ni];
            bf16x4 o;
#pragma unroll
            for (int j = 0; j < 4; ++j) o[j] = (__bf16)v[j];
            *(bf16x4*)(Cout + mrow + bcol + nc) = o;
        }
    }
}

// ---- logits GEMM: BM=128, BN=256, BK=64, 512 threads (8 waves 2x4) ----
// LDS 48KB (A 16 + B 32), 2 blocks/CU (16 waves/CU). Per-wave math identical to r6
// (acc[4][4], 64x64 wave tile). Epilogue: 4 phases x 32 rows via dead LDS (XOR-swizzled),
// each wave store = 1KB contiguous row segment (contiguity lever: 512B -> 1KB).
__global__ void __launch_bounds__(512, 4)
k_logits(const __bf16* __restrict__ A, const __bf16* __restrict__ B,
         float* __restrict__ C, const float* __restrict__ bias,
         float* __restrict__ partials) {
    __shared__ __align__(16) char smem[49152];   // K-loop: A@0 16KB, B@16384 32KB; epi: 32KB
    __shared__ __align__(16) float bias_lds[256];
    __shared__ float wsum[128][4];

    const int tid = threadIdx.x, lane = tid & 63, w = tid >> 6;   // w 0..7
    const int wr = w >> 2, wc = w & 3;                            // 2 x 4 wave grid
    const int brow = blockIdx.x * 128;
    const int bn = blockIdx.y, bcol = bn * 256;
    const int gg = lane >> 4, li = lane & 15;

    if (tid < 256) bias_lds[tid] = (bcol + tid < V_SIZE) ? bias[bcol + tid] : 0.f;

    f32x4 acc[4][4] = {};

#pragma unroll
    for (int t = 0; t < 4; ++t) {
        // A: 1024 chunks, 2/thread
#pragma unroll
        for (int i = 0; i < 2; ++i) {
            int cb = (w * 2 + i) * 64;
            int c = cb + lane;
            int r = c >> 3, kbs = (c & 7) ^ (r & 7);
            GLOAD_LDS16(A + (size_t)(brow + r) * E_DIM + t * 64 + kbs * 8, smem + cb * 16);
        }
        // B: 2048 chunks, 4/thread
#pragma unroll
        for (int i = 0; i < 4; ++i) {
            int cb = (w * 4 + i) * 64;
            int c = cb + lane;
            int r = c >> 3, kbs = (c & 7) ^ (r & 7);
            GLOAD_LDS16(B + (size_t)(bcol + r) * E_DIM + t * 64 + kbs * 8,
                        smem + 16384 + cb * 16);
        }
        __syncthreads();
#pragma unroll
        for (int ks = 0; ks < 2; ++ks) {
            bf16x8 af[4], bfr[4];
#pragma unroll
            for (int mi = 0; mi < 4; ++mi) {
                int r = wr * 64 + mi * 16 + li;
                int kbyte = (ks * 64 + gg * 16) ^ ((r & 7) << 4);
                af[mi] = *(const bf16x8*)(smem + r * 128 + kbyte);
            }
#pragma unroll
            for (int ni = 0; ni < 4; ++ni) {
                int r = wc * 64 + ni * 16 + li;
                int kbyte = (ks * 64 + gg * 16) ^ ((r & 7) << 4);
                bfr[ni] = *(const bf16x8*)(smem + 16384 + r * 128 + kbyte);
            }
            // swapped operands: register dim <-> B rows (n), lane dim <-> A rows (m)
#pragma unroll
            for (int mi = 0; mi < 4; ++mi)
#pragma unroll
                for (int ni = 0; ni < 4; ++ni)
                    acc[mi][ni] = mfma16(bfr[ni], af[mi], acc[mi][ni]);
        }
        if (t < 3) __syncthreads();
    }

    // epilogue: m = brow + wr*64 + mi*16 + li, n = bcol + wc*64 + ni*16 + gg*4 + j
    if (bcol + 256 <= V_SIZE) {
        // 4 phases x 32 rows: stash (XOR-swizzled) then 1KB-contiguous wave stores
#pragma unroll
        for (int p = 0; p < 4; ++p) {
            __syncthreads();                 // LDS free (K-loop done / prev phase stored)
            if (wr == (p >> 1)) {
#pragma unroll
                for (int m2 = 0; m2 < 2; ++m2) {
                    int mi = (p & 1) * 2 + m2;
                    int rl = m2 * 16 + li;   // local row 0..31 (global = brow + p*32 + rl)
                    float s = 0.f;
#pragma unroll
                    for (int ni = 0; ni < 4; ++ni) {
                        int colc = wc * 16 + ni * 4 + gg;   // 16B col-chunk 0..63
                        f32x4 v = acc[mi][ni];
                        f32x4 bv = *(const f32x4*)&bias_lds[colc * 4];
#pragma unroll
                        for (int j = 0; j < 4; ++j) { v[j] += bv[j]; s += __expf(v[j]); }
                        int c4s = colc ^ ((rl & 7) << 2);
                        *(f32x4*)(smem + rl * 1024 + c4s * 16) = v;
                    }
                    s += __shfl_xor(s, 16); s += __shfl_xor(s, 32);
                    if (gg == 0) wsum[p * 32 + rl][wc] = s;
                }
            }
            __syncthreads();
            // all 8 waves stream 32KB: per instr a wave writes 1KB = one full row segment
#pragma unroll
            for (int i = 0; i < 4; ++i) {
                int c = i * 512 + tid;       // 0..2047
                int rl = c >> 6, c4 = c & 63;
                f32x4 v = *(const f32x4*)(smem + rl * 1024 + ((c4 ^ ((rl & 7) << 2)) << 4));
                *(f32x4*)(C + (size_t)(brow + p * 32 + rl) * V_SIZE + bcol + c4 * 4) = v;
            }
        }
    } else {
        // bn == 196: cols 50176..50256 valid (81) — masked register path
#pragma unroll
        for (int mi = 0; mi < 4; ++mi) {
            const size_t mrow = (size_t)(brow + wr * 64 + mi * 16 + li) * V_SIZE;
            float s = 0.f;
#pragma unroll
            for (int ni = 0; ni < 4; ++ni) {
                int nc = wc * 64 + ni * 16 + gg * 4;
#pragma unroll
                for (int j = 0; j < 4; ++j) {
                    int col = bcol + nc + j;
                    if (col < V_SIZE) {
                        float v = acc[mi][ni][j] + bias_lds[nc + j];
                        s += __expf(v);
                        C[mrow + col] = v;
                    }
                }
            }
            s += __shfl_xor(s, 16); s += __shfl_xor(s, 32);
            if (gg == 0) wsum[wr * 64 + mi * 16 + li][wc] = s;
        }
    }
    __syncthreads();
    if (tid < 128)
        partials[(size_t)bn * NROWS + brow + tid] =
            wsum[tid][0] + wsum[tid][1] + wsum[tid][2] + wsum[tid][3];
}

// ---- attention pass 1: column softmax denominators D[bh][k] = sum_{q>=k} exp(scale*q.k) ----
__global__ void __launch_bounds__(256)
k_pass1(const __bf16* __restrict__ QKV, float* __restrict__ Dcol) {
    int p = blockIdx.x;              // 0..135
    int kt = 0;
    while (p >= 16 - kt) { p -= 16 - kt; ++kt; }
    const int qc = kt + p;
    const int bh = blockIdx.y;
    const int b = bh >> 3, h = bh & 7;
    const int tid = threadIdx.x, lane = tid & 63, w = tid >> 6;
    const int g = lane >> 5, li = lane & 31;
    __shared__ __align__(16) __bf16 Klds[4 * 128 * 8];   // [db][k][8]
    __shared__ __align__(16) __bf16 Qlds[4 * 128 * 8];   // [db][q][8]

    const size_t baseQ = ((size_t)b * T_SEQ) * 768 + h * 32;
    const size_t baseK = baseQ + 256;

#pragma unroll
    for (int i = 0; i < 2; ++i) {
        int c = i * 256 + tid; int k = c >> 2, db = c & 3;
        *(bf16x8*)(Klds + (db * 128 + k) * 8) =
            *(const bf16x8*)(QKV + baseK + (size_t)(kt * 128 + k) * 768 + db * 8);
        *(bf16x8*)(Qlds + (db * 128 + k) * 8) =
            *(const bf16x8*)(QKV + baseQ + (size_t)(qc * 128 + k) * 768 + db * 8);
    }
    __syncthreads();

    float csum = 0.f;
    const int kglob = kt * 128 + w * 32 + li;
#pragma unroll
    for (int qs = 0; qs < 4; ++qs) {
        f32x16 sacc = {};
#pragma unroll
        for (int ks = 0; ks < 2; ++ks) {
            bf16x8 aq = *(const bf16x8*)(Qlds + ((ks * 2 + g) * 128 + qs * 32 + li) * 8);
            bf16x8 bk = *(const bf16x8*)(Klds + ((ks * 2 + g) * 128 + w * 32 + li) * 8);
            sacc = mfma32(aq, bk, sacc);   // S[q][k]: col=l&31=k, row=crow(r,g)=q
        }
#pragma unroll
        for (int r = 0; r < 16; ++r) {
            int qrow = qc * 128 + qs * 32 + ((r & 3) + 8 * (r >> 2) + 4 * g);
            if (kglob <= qrow) csum += __expf(sacc[r] * SCALE_QK);
        }
    }
    csum += __shfl_xor(csum, 32);
    if (g == 0) atomicAdd(&Dcol[(size_t)bh * T_SEQ + kglob], csum);
}

// ---- attention pass 2: y[q][h*32+d] = sum_{k<=q} exp(scale*q.k) * v[k][d] / D[k] ----
__global__ void __launch_bounds__(256)
k_pass2(const __bf16* __restrict__ QKV, const float* __restrict__ Dcol,
        float* __restrict__ Yf0, float* __restrict__ Yf1) {
    const int p = blockIdx.x, bh = blockIdx.y;
    const int pi = p >> 1, par = p & 1;
    const int b = bh >> 3, h = bh & 7;
    const int tid = threadIdx.x, lane = tid & 63, w = tid >> 6;
    const int g = lane >> 5, li = lane & 31;
    float* __restrict__ Yf = par ? Yf1 : Yf0;
    __shared__ __align__(16) __bf16 Qlds[4 * 128 * 8];    // [db][q][8]
    __shared__ __align__(16) __bf16 Klds[4 * 128 * 8];    // [db][k][8]
    __shared__ __align__(16) __bf16 UT[16 * 32 * 8];      // [kb][d][8]  (V/D)^T
    __shared__ __align__(16) __bf16 Plds[4][32 * 136];    // per-wave P[q][k], pad 8

    const size_t baseQ = ((size_t)b * T_SEQ) * 768 + h * 32;
    const size_t baseK = baseQ + 256;
    const size_t baseV = baseQ + 512;

#pragma unroll
    for (int ti = 0; ti < 2; ++ti) {
        const int qt = ti ? (15 - pi) : pi;
        __syncthreads();
#pragma unroll
        for (int i = 0; i < 2; ++i) {
            int c = i * 256 + tid; int q = c >> 2, db = c & 3;
            *(bf16x8*)(Qlds + (db * 128 + q) * 8) =
                *(const bf16x8*)(QKV + baseQ + (size_t)(qt * 128 + q) * 768 + db * 8);
        }
        f32x16 oacc = {};
        const int qrow = qt * 128 + w * 32 + li;

        for (int kc = par; kc <= qt; kc += 2) {
            __syncthreads();
#pragma unroll
            for (int i = 0; i < 2; ++i) {
                int c = i * 256 + tid; int k = c >> 2, db = c & 3;
                *(bf16x8*)(Klds + (db * 128 + k) * 8) =
                    *(const bf16x8*)(QKV + baseK + (size_t)(kc * 128 + k) * 768 + db * 8);
            }
#pragma unroll
            for (int i = 0; i < 4; ++i) {
                int c = i * 256 + tid; int k = c & 127, d4 = c >> 7;
                float rD = 1.0f / Dcol[(size_t)bh * T_SEQ + kc * 128 + k];
                bf16x4 v4 = *(const bf16x4*)(QKV + baseV + (size_t)(kc * 128 + k) * 768 + d4 * 4);
                int kb = k >> 3, j = k & 7;
#pragma unroll
                for (int t2 = 0; t2 < 4; ++t2)
                    UT[((size_t)kb * 32 + d4 * 4 + t2) * 8 + j] = (__bf16)((float)v4[t2] * rD);
            }
            __syncthreads();

#pragma unroll
            for (int ksub = 0; ksub < 4; ++ksub) {
                int kbase = kc * 128 + ksub * 32;
                f32x16 sacc = {};
#pragma unroll
                for (int ks = 0; ks < 2; ++ks) {
                    bf16x8 ak = *(const bf16x8*)(Klds + ((ks * 2 + g) * 128 + ksub * 32 + li) * 8);
                    bf16x8 bq = *(const bf16x8*)(Qlds + ((ks * 2 + g) * 128 + w * 32 + li) * 8);
                    sacc = mfma32(ak, bq, sacc);   // S^T: col=l&31=q, row=crow(r,g)=k
                }
                float pv[16];
#pragma unroll
                for (int r = 0; r < 16; ++r) {
                    int kk = kbase + (r & 3) + 8 * (r >> 2) + 4 * g;
                    pv[r] = (kk <= qrow) ? __expf(sacc[r] * SCALE_QK) : 0.f;
                }
#pragma unroll
                for (int t2 = 0; t2 < 4; ++t2) {
                    bf16x4 pk;
#pragma unroll
                    for (int e = 0; e < 4; ++e) pk[e] = (__bf16)pv[4 * t2 + e];
                    *(bf16x4*)(&Plds[w][li * 136 + ksub * 32 + 8 * t2 + 4 * g]) = pk;
                }
            }
#pragma unroll
            for (int ks16 = 0; ks16 < 8; ++ks16) {
                bf16x8 ap = *(const bf16x8*)(&Plds[w][li * 136 + ks16 * 16 + g * 8]);
                bf16x8 bu = *(const bf16x8*)(UT + ((ks16 * 2 + g) * 32 + li) * 8);
                oacc = mfma32(ap, bu, oacc);       // col=l&31=d, row=crow(r,g)=q
            }
        }
#pragma unroll
        for (int r = 0; r < 16; ++r) {
            int q = qt * 128 + w * 32 + (r & 3) + 8 * (r >> 2) + 4 * g;
            Yf[((size_t)b * T_SEQ + q) * E_DIM + h * 32 + li] = oacc[r];
        }
    }
}

// ---- Y = bf16(Yf0 + Yf1) ----
__global__ void k_ycvt(const float* __restrict__ a, const float* __restrict__ b,
                       __bf16* __restrict__ y, int n4) {
    int i = blockIdx.x * 256 + threadIdx.x;
    if (i < n4) {
        f32x4 va = ((const f32x4*)a)[i], vb = ((const f32x4*)b)[i];
        bf16x4 o;
#pragma unroll
        for (int j = 0; j < 4; ++j) o[j] = (__bf16)(va[j] + vb[j]);
        ((bf16x4*)y)[i] = o;
    }
}

// ---- per-row LSE + target gather ----
__global__ void k_rowlse(const float* __restrict__ partials, const float* __restrict__ logits,
                         const int* __restrict__ tgt, float* __restrict__ rowloss) {
    int r = blockIdx.x * 256 + threadIdx.x;   // 0..4095
    float s = 0.f;
    for (int i = 0; i < LNB; ++i) s += partials[(size_t)i * NROWS + r];
    float lse = logf(s);
    rowloss[r] = lse - logits[(size_t)r * V_SIZE + tgt[r]];
}

// ---- final mean ----
__global__ void k_loss(const float* __restrict__ rowloss, float* __restrict__ out) {
    __shared__ float red[4];
    float s = 0.f;
    for (int i = threadIdx.x; i < NROWS; i += 256) s += rowloss[i];
    for (int m = 1; m < 64; m <<= 1) s += __shfl_xor(s, m);
    if ((threadIdx.x & 63) == 0) red[threadIdx.x >> 6] = s;
    __syncthreads();
    if (threadIdx.x == 0) out[0] = (red[0] + red[1] + red[2] + red[3]) / (float)NROWS;
}

extern "C" void kernel_launch(void* const* d_in, const int* in_sizes, int n_in,
                              void* d_out, int out_size, void* d_ws, size_t ws_size,
                              hipStream_t stream) {
    const int*   idx = (const int*)d_in[0];
    const int*   tgt = (const int*)d_in[1];
    const float* tok = (const float*)d_in[2];
    const float* pos = (const float*)d_in[3];
    const float* Wq  = (const float*)d_in[4];
    const float* Wk  = (const float*)d_in[5];
    const float* Wv  = (const float*)d_in[6];
    const float* Wlm = (const float*)d_in[7];
    const float* blm = (const float*)d_in[8];

    float* logits = (float*)d_out;
    float* loss   = logits + (size_t)NROWS * V_SIZE;

    char* ws = (char*)d_ws;
    __bf16* X        = (__bf16*)ws; ws += (size_t)NROWS * E_DIM * 2;
    __bf16* Wqkv     = (__bf16*)ws; ws += (size_t)768 * E_DIM * 2;
    __bf16* QKV      = (__bf16*)ws; ws += (size_t)NROWS * 768 * 2;
    float*  Dcol     = (float*)ws;  ws += (size_t)16 * T_SEQ * 4;
    __bf16* Y        = (__bf16*)ws; ws += (size_t)NROWS * E_DIM * 2;
    float*  Yf0      = (float*)ws;  ws += (size_t)NROWS * E_DIM * 4;
    float*  Yf1      = (float*)ws;  ws += (size_t)NROWS * E_DIM * 4;
    __bf16* WlmB     = (__bf16*)ws; ws += (size_t)NPAD * E_DIM * 2;   // padded to 50432 rows
    float*  partials = (float*)ws;  ws += (size_t)LNB * NROWS * 4;
    float*  rowloss  = (float*)ws;  ws += (size_t)NROWS * 4;

    k_prep<<<PREP_ZERO, 256, 0, stream>>>(idx, tok, pos, X, Wq, Wk, Wv, Wqkv,
                                          Wlm, WlmB, Dcol);
    k_gemm_bt<E_DIM><<<dim3(NROWS / 128, 768 / 128), 256, 0, stream>>>(
        X, Wqkv, QKV, 768);
    k_pass1<<<dim3(136, 16), 256, 0, stream>>>(QKV, Dcol);
    k_pass2<<<dim3(16, 16), 256, 0, stream>>>(QKV, Dcol, Yf0, Yf1);
    k_ycvt<<<(NROWS * E_DIM / 4 + 255) / 256, 256, 0, stream>>>(Yf0, Yf1, Y, NROWS * E_DIM / 4);
    k_logits<<<dim3(NROWS / 128, LNB), 512, 0, stream>>>(
        Y, WlmB, logits, blm, partials);
    k_rowlse<<<NROWS / 256, 256, 0, stream>>>(partials, logits, tgt, rowloss);
    k_loss<<<1, 256, 0, stream>>>(rowloss, loss);
}